// Round 8
// baseline (432.468 us; speedup 1.0000x reference)
//
#include <hip/hip_runtime.h>
#include <cmath>
#include <complex>
#include <vector>

#define NN 4096
#define BB 4
#define CCH 8

// ---- workspace float offsets
#define OFF_W3JVAL 0         // 2670 (pad 2688)
#define OFF_W3JOUT 2688      // 10648 -> 13336 (pad 13440)
#define OFF_CTX0   13568     // 2 partials x 4*4096*96 floats
#define CTXS       1572864
// ---- byte offsets, 16B aligned
#define OFFB_KGH   12640256ULL   // u16[4*4096*32] = 1048576 B
#define OFFB_KGL   13688832ULL
#define OFFB_VGH   14737408ULL   // u16[4*64*96*64] = 3145728 B
#define OFFB_VGL   17883136ULL
#define OFFB_WBH   21028864ULL   // u16[96*160] = 30720 B
#define OFFB_WBL   21059584ULL   // end 21090304

typedef short s16x8 __attribute__((ext_vector_type(8)));
typedef float f32x4 __attribute__((ext_vector_type(4)));
typedef unsigned int u32x4 __attribute__((ext_vector_type(4)));

static __device__ __forceinline__ unsigned short f2bf(float x){
  unsigned u = __float_as_uint(x);
  return (unsigned short)((u + 0x7FFFu + ((u >> 16) & 1u)) >> 16);
}
static __device__ __forceinline__ float bf2f(unsigned short h){
  return __uint_as_float(((unsigned)h) << 16);
}
// trunc split-pack (3 VALU): h=trunc-bf16(v) in low16, l=trunc-bf16(v-h) in high16
static __device__ __forceinline__ unsigned pk2t(float v){
  unsigned uv = __float_as_uint(v);
  float r = v - __uint_as_float(uv & 0xFFFF0000u);
  return __builtin_amdgcn_perm(__float_as_uint(r), uv, 0x07060302u);
}
// RTNE split-pack (for precomputed tables / V)
static __device__ __forceinline__ unsigned pk2r(float v){
  unsigned short h = f2bf(v);
  unsigned short l = f2bf(v - bf2f(h));
  return ((unsigned)l << 16) | (unsigned)h;
}
// unpack 8 packed u32 -> (high s16x8 from low16s, low s16x8 from high16s)
static __device__ __forceinline__ void unpk(u32x4 a, u32x4 b, s16x8& h, s16x8& l){
  u32x4 hw = { __builtin_amdgcn_perm(a[1],a[0],0x05040100u),
               __builtin_amdgcn_perm(a[3],a[2],0x05040100u),
               __builtin_amdgcn_perm(b[1],b[0],0x05040100u),
               __builtin_amdgcn_perm(b[3],b[2],0x05040100u)};
  u32x4 lw = { __builtin_amdgcn_perm(a[1],a[0],0x07060302u),
               __builtin_amdgcn_perm(a[3],a[2],0x07060302u),
               __builtin_amdgcn_perm(b[1],b[0],0x07060302u),
               __builtin_amdgcn_perm(b[3],b[2],0x07060302u)};
  h = __builtin_bit_cast(s16x8, hw);
  l = __builtin_bit_cast(s16x8, lw);
}

// ---------------------------------------------------------------- host: Wigner 3j
namespace {
double dfact(int n){ double r=1.0; for(int i=2;i<=n;++i) r*=(double)i; return r; }

void compute_w3j(int l1,int l2,int l3,double scale,float* dst){
  int d1=2*l1+1,d2=2*l2+1,d3=2*l3+1;
  std::vector<double> Cc((size_t)d1*d2*d3,0.0);
  for(int i=0;i<d1;i++){int m1=i-l1;
   for(int j=0;j<d2;j++){int m2=j-l2;
    for(int k=0;k<d3;k++){int m3=k-l3;
      if(m1+m2!=m3) continue;
      double pref = std::sqrt((2.0*l3+1.0)*dfact(l3+l1-l2)*dfact(l3-l1+l2)*dfact(l1+l2-l3)/dfact(l1+l2+l3+1));
      pref *= std::sqrt(dfact(l3+m3)*dfact(l3-m3)*dfact(l1-m1)*dfact(l1+m1)*dfact(l2-m2)*dfact(l2+m2));
      double s=0.0;
      for(int kk=0;kk<=l1+l2-l3;kk++){
        int dd[6]={kk,l1+l2-l3-kk,l1-m1-kk,l2+m2-kk,l3-l2+m1+kk,l3-l1-m2+kk};
        int mn=dd[0]; for(int t=1;t<6;t++) if(dd[t]<mn) mn=dd[t];
        if(mn<0) continue;
        double prod=1.0; for(int t=0;t<6;t++) prod*=dfact(dd[t]);
        s += ((kk&1)?-1.0:1.0)/prod;
      }
      Cc[((size_t)i*d2+j)*d3+k]=pref*s;
    }}}
  auto qmat=[](int l){
    int d=2*l+1;
    std::vector<std::complex<double>> q((size_t)d*d,std::complex<double>(0,0));
    double rs2=1.0/std::sqrt(2.0);
    for(int m=-l;m<0;m++){
      q[(size_t)(l+m)*d+(l-m)]=std::complex<double>(rs2,0);
      q[(size_t)(l+m)*d+(l+m)]=std::complex<double>(0,-rs2);
    }
    q[(size_t)l*d+l]=std::complex<double>(1,0);
    for(int m=1;m<=l;m++){
      double sg=(m&1)?-1.0:1.0;
      q[(size_t)(l+m)*d+(l+m)]=std::complex<double>(sg*rs2,0);
      q[(size_t)(l+m)*d+(l-m)]=std::complex<double>(0,sg*rs2);
    }
    std::complex<double> f(1,0),mi(0,-1);
    for(int t=0;t<l;t++) f*=mi;
    for(auto&z:q) z*=f;
    return q;
  };
  auto Q1=qmat(l1),Q2=qmat(l2),Q3=qmat(l3);
  std::vector<std::complex<double>> T1((size_t)d1*d2*d3), T2((size_t)d1*d2*d3);
  for(int j=0;j<d1;j++) for(int k=0;k<d2;k++) for(int m=0;m<d3;m++){
    std::complex<double> s(0,0);
    for(int i=0;i<d1;i++) s += Q1[(size_t)i*d1+j]*Cc[((size_t)i*d2+k)*d3+m];
    T1[((size_t)j*d2+k)*d3+m]=s;
  }
  for(int j=0;j<d1;j++) for(int l=0;l<d2;l++) for(int m=0;m<d3;m++){
    std::complex<double> s(0,0);
    for(int k=0;k<d2;k++) s += Q2[(size_t)k*d2+l]*T1[((size_t)j*d2+k)*d3+m];
    T2[((size_t)j*d2+l)*d3+m]=s;
  }
  std::vector<double> Cr((size_t)d1*d2*d3);
  double nrm=0.0;
  for(int j=0;j<d1;j++) for(int l=0;l<d2;l++) for(int n=0;n<d3;n++){
    std::complex<double> s(0,0);
    for(int m=0;m<d3;m++) s += std::conj(Q3[(size_t)m*d3+n])*T2[((size_t)j*d2+l)*d3+m];
    double v=s.real();
    Cr[((size_t)j*d2+l)*d3+n]=v; nrm+=v*v;
  }
  nrm=std::sqrt(nrm);
  double c=scale/nrm;
  for(size_t t=0;t<Cr.size();t++) dst[t]=(float)(Cr[t]*c);
}
} // namespace

// ---------------------------------------------------------------- k_weights
// Builds WB[96 features][160 k-cols] split-bf16 (RTNE): folds w3j with
// A[p][i3] = sum_w scal[p][w]*bw[valpath][w]. P cols: c<54: l1=4 (i=c/6, jj=c%6),
// 54..131: l1=6, 132: const-1 (denominator), >=133: zero. jj indexes sh[0..5].
__global__ void k_weights(const float* __restrict__ wli, const float* __restrict__ wval,
                          const float* __restrict__ wout, const float* __restrict__ wlo,
                          const float* __restrict__ Wv,
                          unsigned short* __restrict__ WBH, unsigned short* __restrict__ WBL){
  __shared__ float bws[48];
  __shared__ float scs[64];
  __shared__ float As[24];
  int t = threadIdx.x;
  if(t<48){
    const int val_l1[6]={0,0,1,0,1,1};
    int p=t>>3, w=t&7;
    float s=0.f;
    for(int u=0;u<8;u++) s = fmaf(wli[val_l1[p]*8+u], wval[(p*8+u)*8+w], s);
    bws[t]=s;
  }
  {
    const int out_l1[8]={0,0,1,1,0,0,1,1};
    const int out_l3[8]={0,0,0,0,1,1,1,1};
    int p=t>>3, v=t&7;
    float s=0.f;
    for(int u=0;u<8;u++){
      float a=wli[out_l1[p]*8+u];
      for(int w=0;w<8;w++) s = fmaf(wout[((p*8+u)*8+v)*8+w]*a, wlo[out_l3[p]*8+w], s);
    }
    scs[t]=s*0.35355339059327373f; // 1/sqrt(8)
  }
  __syncthreads();
  if(t<24){
    int p=t/3, i3=t-3*p;
    int vp = (p&1)*3 + i3;
    float s=0.f;
    for(int w=0;w<8;w++) s = fmaf(scs[p*8+w], bws[vp*8+w], s);
    As[t]=s;
  }
  __syncthreads();
  for(int cell=t; cell<96*160; cell+=64){
    int f = cell/160, c = cell - f*160;
    float v = 0.f;
    if(f < 88 && c < 132){
      int seg = f/22, off = f - seg*22;
      int even = (off < 9);
      int p = 2*seg + (even?0:1);
      int jo = even ? off : off-9;
      int l1, i, jj;
      if(c < 54){ l1=4; i=c/6; jj=c-6*i; }
      else { int cc=c-54; l1=6; i=cc/6; jj=cc-6*i; }
      if(even){
        if(l1==4 && jj==0)      v = As[p*3+0]*Wv[i*9+jo];
        else if(l1==4)          v = As[p*3+1]*Wv[81+(i*5+jj-1)*9+jo];
        else if(jj>=1)          v = As[p*3+2]*Wv[486+(i*5+jj-1)*9+jo];
      } else {
        if(l1==4 && jj>=1)      v = As[p*3+0]*Wv[1071+(i*5+jj-1)*13+jo];
        else if(l1==6 && jj==0) v = As[p*3+1]*Wv[1656+i*13+jo];
        else if(l1==6)          v = As[p*3+2]*Wv[1825+(i*5+jj-1)*13+jo];
      }
    } else if(f==88 && c==132){
      v = 1.0f;
    }
    unsigned short h = f2bf(v);
    WBH[cell] = h;
    WBL[cell] = f2bf(v - bf2f(h));
  }
}

// ---------------------------------------------------------------- k_prep (MFMA)
// grid 256 x 64 thr: one wave per 64-point panel. Lane = point.
// P[point][160] packed split-bf16 (RTNE) in LDS; V = (P @ WB)*epb via split-4 MFMA;
// epilogue transposes through LDS to [panel][96][64] split u16 h/l.
// Also emits split-bf16 K rows [idx][32].
#define PST 164
__launch_bounds__(64,1)
__global__ void k_prep(const float* __restrict__ feat, const float* __restrict__ sh,
                       const float* __restrict__ log_s, const float* __restrict__ pos_w,
                       const float* __restrict__ pos_b,
                       const unsigned short* __restrict__ WBH,
                       const unsigned short* __restrict__ WBL,
                       unsigned short* __restrict__ Kgh, unsigned short* __restrict__ Kgl,
                       unsigned short* __restrict__ Vgh, unsigned short* __restrict__ Vgl){
  __shared__ __align__(16) unsigned int Pbuf[64*PST];   // 41984 B; reused as Po[96][68]
  __shared__ float epbs[64];
  int tid = threadIdx.x;           // lane == point-in-panel
  int lm = tid & 15, quad = tid >> 4;
  int idx = blockIdx.x*64 + tid;
  int n = idx & (NN-1);
  const float* fp = feat + (size_t)idx*22;
  const float* shp = sh + n*6;
  float f[22];
  #pragma unroll
  for(int c=0;c<22;c++) f[c]=fp[c];
  float y[6];
  #pragma unroll
  for(int j=0;j<6;j++) y[j]=shp[j];
  // ---- K rows
  {
    float n4=0.f, n6=0.f;
    #pragma unroll
    for(int c=0;c<9;c++) n4 += f[c]*f[c];
    #pragma unroll
    for(int c=9;c<22;c++) n6 += f[c]*f[c];
    n4 = fmaxf(sqrtf(n4), 1e-12f);
    n6 = fmaxf(sqrtf(n6), 1e-12f);
    float s4 = __expf(log_s[0]), s6 = __expf(log_s[1]);
    float a4 = sqrtf(s4)/n4, a6 = sqrtf(s6)/n6;
    unsigned short* kph = Kgh + (size_t)idx*32;
    unsigned short* kpl = Kgl + (size_t)idx*32;
    #pragma unroll
    for(int c=0;c<22;c++){
      float qv = f[c] * (c<9 ? a4 : a6);
      unsigned short h = f2bf(qv);
      kph[c]=h; kpl[c]=f2bf(qv - bf2f(h));
    }
    #pragma unroll
    for(int c=22;c<32;c++){ kph[c]=0; kpl[c]=0; }
  }
  // ---- epb
  {
    float pb = pos_b[0];
    #pragma unroll
    for(int j=0;j<6;j++) pb = fmaf(y[j], pos_w[j], pb);
    epbs[tid] = __expf(pb);
  }
  // ---- build P row (packed split-bf16, RTNE)
  #pragma unroll
  for(int c4=0;c4<40;c4++){
    u32x4 w;
    #pragma unroll
    for(int e=0;e<4;e++){
      int c = 4*c4+e;
      float pv;
      if(c<54){ int i=c/6, jj=c-6*i; pv = f[i]*y[jj]; }
      else if(c<132){ int cc=c-54; int i=cc/6, jj=cc-6*i; pv = f[9+i]*y[jj]; }
      else if(c==132) pv = 1.0f;
      else pv = 0.0f;
      w[e] = pk2r(pv);
    }
    *(u32x4*)&Pbuf[tid*PST + 4*c4] = w;
  }
  __syncthreads();
  // ---- MFMA: out[64 pts][96 g] = P @ WB (split-4)
  f32x4 acc[4][6];
  #pragma unroll
  for(int mt=0;mt<4;mt++)
    #pragma unroll
    for(int ft=0;ft<6;ft++)
      #pragma unroll
      for(int i=0;i<4;i++) acc[mt][ft][i]=0.f;
  for(int kc=0;kc<5;kc++){
    s16x8 Ah[4], Al[4];
    #pragma unroll
    for(int mt=0;mt<4;mt++){
      const u32x4* ap = (const u32x4*)&Pbuf[(mt*16+lm)*PST + kc*32 + quad*8];
      unpk(ap[0], ap[1], Ah[mt], Al[mt]);
    }
    #pragma unroll
    for(int ft=0;ft<6;ft++){
      size_t bo = (size_t)(ft*16+lm)*160 + kc*32 + quad*8;
      s16x8 Bh = *(const s16x8*)(WBH + bo);
      s16x8 Bl = *(const s16x8*)(WBL + bo);
      #pragma unroll
      for(int mt=0;mt<4;mt++){
        f32x4 a = acc[mt][ft];
        a = __builtin_amdgcn_mfma_f32_16x16x32_bf16(Al[mt], Bl, a, 0,0,0);
        a = __builtin_amdgcn_mfma_f32_16x16x32_bf16(Al[mt], Bh, a, 0,0,0);
        a = __builtin_amdgcn_mfma_f32_16x16x32_bf16(Ah[mt], Bl, a, 0,0,0);
        a = __builtin_amdgcn_mfma_f32_16x16x32_bf16(Ah[mt], Bh, a, 0,0,0);
        acc[mt][ft] = a;
      }
    }
  }
  __syncthreads();   // P dead; Pbuf reused as Po
  // ---- epilogue: C[pt=mt*16+quad*4+r][g=ft*16+lm] * epb -> Po[g][pt] (RTNE)
  #pragma unroll
  for(int mt=0;mt<4;mt++){
    #pragma unroll
    for(int r=0;r<4;r++){
      float e = epbs[mt*16 + quad*4 + r];
      #pragma unroll
      for(int ft=0;ft<6;ft++){
        Pbuf[(ft*16+lm)*68 + mt*16 + quad*4 + r] = pk2r(acc[mt][ft][r]*e);
      }
    }
  }
  __syncthreads();
  // ---- coalesced flush: Vg [panel][g][64]
  unsigned short* vh = Vgh + (size_t)blockIdx.x*96*64 + tid;
  unsigned short* vl = Vgl + (size_t)blockIdx.x*96*64 + tid;
  for(int g=0;g<96;g++){
    unsigned u = Pbuf[g*68 + tid];
    vh[(size_t)g*64] = (unsigned short)u;
    vl[(size_t)g*64] = (unsigned short)(u>>16);
  }
}

// ---------------------------------------------------------------- k_attn
// grid 256 = b(slow) x 2kh x 32qb; block 512 (8 waves). Wave = one 16-row q-tile,
// all 96 features, 2048 keys. NO __syncthreads: E transposed C->A layout through
// wave-PRIVATE LDS (in-order DS pipe per wave; wave_barrier pins compiler order).
#define EWST 68   // u32 row stride: conflict-free b128 writes & reads (verified)
__launch_bounds__(512, 2)
__global__ void k_attn(const unsigned short* __restrict__ Kgh,
                       const unsigned short* __restrict__ Kgl,
                       const unsigned short* __restrict__ Vgh,
                       const unsigned short* __restrict__ Vgl,
                       float* __restrict__ ctx0){
  __shared__ __align__(16) unsigned int Ew[8*16*EWST];   // 34816 B
  int tid = threadIdx.x;
  int lane = tid & 63, w = tid >> 6;
  int lm = lane & 15, quad = lane >> 4;
  int blk = blockIdx.x;
  int qb = blk & 31, kh = (blk>>5)&1, b = blk >> 6;
  int qt0 = qb*128 + w*16;                           // this wave's q rows
  const unsigned short* KhB = Kgh + (size_t)b*NN*32;
  const unsigned short* KlB = Kgl + (size_t)b*NN*32;
  const unsigned short* VhB = Vgh + (size_t)b*64*96*64;
  const unsigned short* VlB = Vgl + (size_t)b*64*96*64;
  float* ctx = ctx0 + (size_t)kh*CTXS + (size_t)b*NN*96;
  unsigned int* ew = &Ew[w*(16*EWST)];

  s16x8 qh, ql;
  {
    size_t ro = (size_t)(qt0 + lm)*32 + (size_t)quad*8;
    qh = *(const s16x8*)(KhB + ro);
    ql = *(const s16x8*)(KlB + ro);
  }
  f32x4 acc[6];
  #pragma unroll
  for(int ft=0;ft<6;ft++)
    #pragma unroll
    for(int i=0;i<4;i++) acc[ft][i]=0.f;

  #pragma unroll 1
  for(int it=0; it<32; ++it){
    int panel = kh*32 + it;
    int key0 = panel*64;
    // K loads (this iter)
    s16x8 k4h[4], k4l[4];
    #pragma unroll
    for(int t=0;t<4;t++){
      size_t ko = (size_t)(key0 + t*16 + lm)*32 + (size_t)quad*8;
      k4h[t] = *(const s16x8*)(KhB + ko);
      k4l[t] = *(const s16x8*)(KlB + ko);
    }
    // S^T: A=K, B=Q -> D[m=quad*4+r (+16t)][q=lm]
    f32x4 sacc[4];
    #pragma unroll
    for(int t=0;t<4;t++){
      f32x4 s = {0.f,0.f,0.f,0.f};
      s = __builtin_amdgcn_mfma_f32_16x16x32_bf16(k4l[t], qh, s, 0,0,0);
      s = __builtin_amdgcn_mfma_f32_16x16x32_bf16(k4h[t], ql, s, 0,0,0);
      s = __builtin_amdgcn_mfma_f32_16x16x32_bf16(k4h[t], qh, s, 0,0,0);
      sacc[t]=s;
    }
    // V loads staged (issue early; land during exp/transpose)
    s16x8 vhS[2][6], vlS[2][6];
    #pragma unroll
    for(int c=0;c<2;c++)
      #pragma unroll
      for(int ft=0;ft<6;ft++){
        size_t vo = (size_t)panel*96*64 + (size_t)(ft*16+lm)*64 + c*32 + quad*8;
        vhS[c][ft] = *(const s16x8*)(VhB + vo);
        vlS[c][ft] = *(const s16x8*)(VlB + vo);
      }
    // exp + pack, store C-layout rows: ew[q=lm][m = t*16 + quad*4 + r]
    #pragma unroll
    for(int t=0;t<4;t++){
      u32x4 pv;
      #pragma unroll
      for(int r=0;r<4;r++) pv[r] = pk2t(__expf(sacc[t][r]));
      *(u32x4*)&ew[lm*EWST + t*16 + quad*4] = pv;
    }
    __builtin_amdgcn_wave_barrier();   // order: stores above, reads below
    // PV per 32-key chunk: read A-layout E rows, MFMA with staged V
    #pragma unroll
    for(int c=0;c<2;c++){
      const u32x4* pp = (const u32x4*)&ew[lm*EWST + c*32 + quad*8];
      u32x4 pa = pp[0], pb2 = pp[1];
      s16x8 eh, el;
      unpk(pa, pb2, eh, el);
      #pragma unroll
      for(int ft=0;ft<6;ft++){
        f32x4 a = acc[ft];
        a = __builtin_amdgcn_mfma_f32_16x16x32_bf16(el, vhS[c][ft], a, 0,0,0);
        a = __builtin_amdgcn_mfma_f32_16x16x32_bf16(eh, vlS[c][ft], a, 0,0,0);
        a = __builtin_amdgcn_mfma_f32_16x16x32_bf16(eh, vhS[c][ft], a, 0,0,0);
        acc[ft] = a;
      }
    }
    __builtin_amdgcn_wave_barrier();   // reads above complete before next iter's stores
  }
  // epilogue: D[q][f]: row q = qt0 + quad*4 + r, col f = ft*16 + lm
  #pragma unroll
  for(int ft=0;ft<6;ft++){
    int col = ft*16 + lm;
    #pragma unroll
    for(int r=0;r<4;r++){
      int row = qt0 + quad*4 + r;
      ctx[(size_t)row*96 + col] = acc[ft][r];
    }
  }
}

// ---------------------------------------------------------------- k_out
// block = 8 points x 32 lanes; g = sum of 2 ctx partials (already sc-contracted)
__launch_bounds__(256, 4)
__global__ void k_out(const float* __restrict__ feat, const float* __restrict__ ctxA,
                      const float* __restrict__ w3jout, float* __restrict__ out){
  __shared__ float Wo[10648];
  __shared__ float g[8][96];
  __shared__ float fs[8][24];
  __shared__ float inv[8];
  int tid = threadIdx.x;
  for(int i=tid;i<10648;i+=256) Wo[i]=w3jout[i];
  int p = tid>>5, l5 = tid&31;
  int idx = blockIdx.x*8 + p;
  const float* cp0 = ctxA + (size_t)idx*96;
  const float* cp1 = cp0 + CTXS;
  if(l5<22) fs[p][l5] = feat[(size_t)idx*22 + l5];
  if(l5==22) inv[p] = 1.0f / (cp0[88]+cp1[88]);
  for(int gi=l5; gi<88; gi+=32)
    g[p][gi] = cp0[gi]+cp1[gi];
  __syncthreads();
  if(l5 < 22){
    int grp = (l5 < 9) ? 0 : 1;
    int kk  = grp ? (l5-9) : l5;
    int KD  = grp ? 13 : 9;
    float d = 0.f;
    const int IDs[4]={9,9,13,13}, JDs[4]={9,13,9,13}, FBs[4]={0,0,9,9};
    const int WoOff[8]={0,729,1782,2835,4356,5409,6930,8451};
    const int Goff[8]={0,9,22,31,44,53,66,75};
    #pragma unroll
    for(int s4=0;s4<4;s4++){
      const int ID=IDs[s4], JD=JDs[s4], FB=FBs[s4];
      int wb = (grp ? WoOff[s4+4] : WoOff[s4]) + kk;
      int gb = (grp ? Goff[s4+4] : Goff[s4]);
      for(int i=0;i<ID;i++){
        float fi = fs[p][FB+i];
        for(int j=0;j<JD;j++){
          d = fmaf(fi*g[p][gb+j], Wo[wb + (i*JD+j)*KD], d);
        }
      }
    }
    out[(size_t)idx*22 + l5] = d * inv[p];
  }
}

// ---------------------------------------------------------------- launch
extern "C" void kernel_launch(void* const* d_in, const int* in_sizes, int n_in,
                              void* d_out, int out_size, void* d_ws, size_t ws_size,
                              hipStream_t stream){
  (void)in_sizes; (void)n_in; (void)out_size; (void)ws_size;
  static float h_tab[13336];
  {
    const int vpth[6][3]={{4,0,4},{4,2,4},{6,2,4},{4,2,6},{6,0,6},{6,2,6}};
    const int voff[6]={0,81,486,1071,1656,1825};
    for(int p=0;p<6;p++){
      double scl = std::sqrt((2.0*vpth[p][2]+1.0)/(3.0*CCH));
      compute_w3j(vpth[p][0],vpth[p][1],vpth[p][2],scl,h_tab+voff[p]);
    }
    const int opth[8][3]={{4,4,4},{4,6,4},{6,4,4},{6,6,4},{4,4,6},{4,6,6},{6,4,6},{6,6,6}};
    const int ooff[8]={0,729,1782,2835,4356,5409,6930,8451};
    for(int p=0;p<8;p++){
      double scl = std::sqrt((2.0*opth[p][2]+1.0)/(4.0*CCH*CCH));
      compute_w3j(opth[p][0],opth[p][1],opth[p][2],scl,h_tab+2688+ooff[p]);
    }
  }
  float* wsf=(float*)d_ws;
  hipMemcpyAsync(wsf, h_tab, sizeof(h_tab), hipMemcpyHostToDevice, stream);

  const float* feat =(const float*)d_in[0];
  const float* sh   =(const float*)d_in[1];
  const float* log_s=(const float*)d_in[2];
  const float* pos_w=(const float*)d_in[3];
  const float* pos_b=(const float*)d_in[4];
  const float* wli  =(const float*)d_in[5];
  const float* wval =(const float*)d_in[6];
  const float* wout =(const float*)d_in[7];
  const float* wlo  =(const float*)d_in[8];
  float* outp=(float*)d_out;

  unsigned short* Kgh=(unsigned short*)((char*)d_ws + OFFB_KGH);
  unsigned short* Kgl=(unsigned short*)((char*)d_ws + OFFB_KGL);
  unsigned short* Vgh=(unsigned short*)((char*)d_ws + OFFB_VGH);
  unsigned short* Vgl=(unsigned short*)((char*)d_ws + OFFB_VGL);
  unsigned short* WBH=(unsigned short*)((char*)d_ws + OFFB_WBH);
  unsigned short* WBL=(unsigned short*)((char*)d_ws + OFFB_WBL);

  hipLaunchKernelGGL(k_weights, dim3(1), dim3(64), 0, stream,
                     wli, wval, wout, wlo, wsf+OFF_W3JVAL, WBH, WBL);
  hipLaunchKernelGGL(k_prep, dim3(256), dim3(64), 0, stream,
                     feat, sh, log_s, pos_w, pos_b, WBH, WBL,
                     Kgh, Kgl, Vgh, Vgl);
  hipLaunchKernelGGL(k_attn, dim3(256), dim3(512), 0, stream,
                     Kgh, Kgl, Vgh, Vgl, wsf+OFF_CTX0);
  hipLaunchKernelGGL(k_out, dim3(2048), dim3(256), 0, stream,
                     feat, wsf+OFF_CTX0, wsf+OFF_W3JOUT, outp);
}

// Round 9
// 284.296 us; speedup vs baseline: 1.5212x; 1.5212x over previous
//
#include <hip/hip_runtime.h>
#include <cmath>
#include <complex>
#include <vector>

#define NN 4096
#define BB 4
#define CCH 8

// ---- workspace float offsets
#define OFF_W3JVAL 0         // 2670 (pad 2688)
#define OFF_W3JOUT 2688      // 10648 -> 13336 (pad 13440)
#define OFF_CTX0   13568     // 2 partials x 4*4096*96 floats -> ends 6305024 fl
#define CTXS       1572864
// ---- byte offsets, 16B aligned
#define OFFB_KGH   12640256ULL   // u16[4*4096*32] = 1048576 B
#define OFFB_KGL   13688832ULL
#define OFFB_VG    14737408ULL   // u16[4*64*96*64] fp16 = 3145728 B
#define OFFB_WBH   17883136ULL   // u16[96*160] = 30720 B
#define OFFB_WBL   17913856ULL   // end 17944576

typedef short s16x8 __attribute__((ext_vector_type(8)));
typedef _Float16 f16x8 __attribute__((ext_vector_type(8)));
typedef float f32x4 __attribute__((ext_vector_type(4)));
typedef unsigned int u32x4 __attribute__((ext_vector_type(4)));
typedef unsigned int u32x2 __attribute__((ext_vector_type(2)));

static __device__ __forceinline__ unsigned short f2bf(float x){
  unsigned u = __float_as_uint(x);
  return (unsigned short)((u + 0x7FFFu + ((u >> 16) & 1u)) >> 16);
}
static __device__ __forceinline__ float bf2f(unsigned short h){
  return __uint_as_float(((unsigned)h) << 16);
}
// RTNE split-pack bf16: h in low16, l in high16
static __device__ __forceinline__ unsigned pk2r(float v){
  unsigned short h = f2bf(v);
  unsigned short l = f2bf(v - bf2f(h));
  return ((unsigned)l << 16) | (unsigned)h;
}
// fp16 RTNE
static __device__ __forceinline__ unsigned short f2h(float x){
  return __builtin_bit_cast(unsigned short, (_Float16)x);
}
// unpack 8 packed u32 -> (high s16x8 from low16s, low s16x8 from high16s)
static __device__ __forceinline__ void unpk(u32x4 a, u32x4 b, s16x8& h, s16x8& l){
  u32x4 hw = { __builtin_amdgcn_perm(a[1],a[0],0x05040100u),
               __builtin_amdgcn_perm(a[3],a[2],0x05040100u),
               __builtin_amdgcn_perm(b[1],b[0],0x05040100u),
               __builtin_amdgcn_perm(b[3],b[2],0x05040100u)};
  u32x4 lw = { __builtin_amdgcn_perm(a[1],a[0],0x07060302u),
               __builtin_amdgcn_perm(a[3],a[2],0x07060302u),
               __builtin_amdgcn_perm(b[1],b[0],0x07060302u),
               __builtin_amdgcn_perm(b[3],b[2],0x07060302u)};
  h = __builtin_bit_cast(s16x8, hw);
  l = __builtin_bit_cast(s16x8, lw);
}

// ---------------------------------------------------------------- host: Wigner 3j
namespace {
double dfact(int n){ double r=1.0; for(int i=2;i<=n;++i) r*=(double)i; return r; }

void compute_w3j(int l1,int l2,int l3,double scale,float* dst){
  int d1=2*l1+1,d2=2*l2+1,d3=2*l3+1;
  std::vector<double> Cc((size_t)d1*d2*d3,0.0);
  for(int i=0;i<d1;i++){int m1=i-l1;
   for(int j=0;j<d2;j++){int m2=j-l2;
    for(int k=0;k<d3;k++){int m3=k-l3;
      if(m1+m2!=m3) continue;
      double pref = std::sqrt((2.0*l3+1.0)*dfact(l3+l1-l2)*dfact(l3-l1+l2)*dfact(l1+l2-l3)/dfact(l1+l2+l3+1));
      pref *= std::sqrt(dfact(l3+m3)*dfact(l3-m3)*dfact(l1-m1)*dfact(l1+m1)*dfact(l2-m2)*dfact(l2+m2));
      double s=0.0;
      for(int kk=0;kk<=l1+l2-l3;kk++){
        int dd[6]={kk,l1+l2-l3-kk,l1-m1-kk,l2+m2-kk,l3-l2+m1+kk,l3-l1-m2+kk};
        int mn=dd[0]; for(int t=1;t<6;t++) if(dd[t]<mn) mn=dd[t];
        if(mn<0) continue;
        double prod=1.0; for(int t=0;t<6;t++) prod*=dfact(dd[t]);
        s += ((kk&1)?-1.0:1.0)/prod;
      }
      Cc[((size_t)i*d2+j)*d3+k]=pref*s;
    }}}
  auto qmat=[](int l){
    int d=2*l+1;
    std::vector<std::complex<double>> q((size_t)d*d,std::complex<double>(0,0));
    double rs2=1.0/std::sqrt(2.0);
    for(int m=-l;m<0;m++){
      q[(size_t)(l+m)*d+(l-m)]=std::complex<double>(rs2,0);
      q[(size_t)(l+m)*d+(l+m)]=std::complex<double>(0,-rs2);
    }
    q[(size_t)l*d+l]=std::complex<double>(1,0);
    for(int m=1;m<=l;m++){
      double sg=(m&1)?-1.0:1.0;
      q[(size_t)(l+m)*d+(l+m)]=std::complex<double>(sg*rs2,0);
      q[(size_t)(l+m)*d+(l-m)]=std::complex<double>(0,sg*rs2);
    }
    std::complex<double> f(1,0),mi(0,-1);
    for(int t=0;t<l;t++) f*=mi;
    for(auto&z:q) z*=f;
    return q;
  };
  auto Q1=qmat(l1),Q2=qmat(l2),Q3=qmat(l3);
  std::vector<std::complex<double>> T1((size_t)d1*d2*d3), T2((size_t)d1*d2*d3);
  for(int j=0;j<d1;j++) for(int k=0;k<d2;k++) for(int m=0;m<d3;m++){
    std::complex<double> s(0,0);
    for(int i=0;i<d1;i++) s += Q1[(size_t)i*d1+j]*Cc[((size_t)i*d2+k)*d3+m];
    T1[((size_t)j*d2+k)*d3+m]=s;
  }
  for(int j=0;j<d1;j++) for(int l=0;l<d2;l++) for(int m=0;m<d3;m++){
    std::complex<double> s(0,0);
    for(int k=0;k<d2;k++) s += Q2[(size_t)k*d2+l]*T1[((size_t)j*d2+k)*d3+m];
    T2[((size_t)j*d2+l)*d3+m]=s;
  }
  std::vector<double> Cr((size_t)d1*d2*d3);
  double nrm=0.0;
  for(int j=0;j<d1;j++) for(int l=0;l<d2;l++) for(int n=0;n<d3;n++){
    std::complex<double> s(0,0);
    for(int m=0;m<d3;m++) s += std::conj(Q3[(size_t)m*d3+n])*T2[((size_t)j*d2+l)*d3+m];
    double v=s.real();
    Cr[((size_t)j*d2+l)*d3+n]=v; nrm+=v*v;
  }
  nrm=std::sqrt(nrm);
  double c=scale/nrm;
  for(size_t t=0;t<Cr.size();t++) dst[t]=(float)(Cr[t]*c);
}
} // namespace

// ---------------------------------------------------------------- k_weights
// grid 16 x 64. Builds WB[96][160] split-bf16; folds w3j with A[p][i3].
__global__ void k_weights(const float* __restrict__ wli, const float* __restrict__ wval,
                          const float* __restrict__ wout, const float* __restrict__ wlo,
                          const float* __restrict__ Wv,
                          unsigned short* __restrict__ WBH, unsigned short* __restrict__ WBL){
  __shared__ float bws[48];
  __shared__ float scs[64];
  __shared__ float As[24];
  int t = threadIdx.x;
  if(t<48){
    const int val_l1[6]={0,0,1,0,1,1};
    int p=t>>3, w=t&7;
    float s=0.f;
    for(int u=0;u<8;u++) s = fmaf(wli[val_l1[p]*8+u], wval[(p*8+u)*8+w], s);
    bws[t]=s;
  }
  {
    const int out_l1[8]={0,0,1,1,0,0,1,1};
    const int out_l3[8]={0,0,0,0,1,1,1,1};
    int p=t>>3, v=t&7;
    float s=0.f;
    for(int u=0;u<8;u++){
      float a=wli[out_l1[p]*8+u];
      for(int w=0;w<8;w++) s = fmaf(wout[((p*8+u)*8+v)*8+w]*a, wlo[out_l3[p]*8+w], s);
    }
    scs[t]=s*0.35355339059327373f; // 1/sqrt(8)
  }
  __syncthreads();
  if(t<24){
    int p=t/3, i3=t-3*p;
    int vp = (p&1)*3 + i3;
    float s=0.f;
    for(int w=0;w<8;w++) s = fmaf(scs[p*8+w], bws[vp*8+w], s);
    As[t]=s;
  }
  __syncthreads();
  int base = blockIdx.x*960;
  for(int k=0;k<15;k++){
    int cell = base + k*64 + t;
    int f = cell/160, c = cell - f*160;
    float v = 0.f;
    if(f < 88 && c < 132){
      int seg = f/22, off = f - seg*22;
      int even = (off < 9);
      int p = 2*seg + (even?0:1);
      int jo = even ? off : off-9;
      int l1, i, jj;
      if(c < 54){ l1=4; i=c/6; jj=c-6*i; }
      else { int cc=c-54; l1=6; i=cc/6; jj=cc-6*i; }
      if(even){
        if(l1==4 && jj==0)      v = As[p*3+0]*Wv[i*9+jo];
        else if(l1==4)          v = As[p*3+1]*Wv[81+(i*5+jj-1)*9+jo];
        else if(jj>=1)          v = As[p*3+2]*Wv[486+(i*5+jj-1)*9+jo];
      } else {
        if(l1==4 && jj>=1)      v = As[p*3+0]*Wv[1071+(i*5+jj-1)*13+jo];
        else if(l1==6 && jj==0) v = As[p*3+1]*Wv[1656+i*13+jo];
        else if(l1==6)          v = As[p*3+2]*Wv[1825+(i*5+jj-1)*13+jo];
      }
    } else if(f==88 && c==132){
      v = 1.0f;
    }
    unsigned short h = f2bf(v);
    WBH[cell] = h;
    WBL[cell] = f2bf(v - bf2f(h));
  }
}

// ---------------------------------------------------------------- k_prep (MFMA)
// grid 1024 x 64: block = (panel = blk>>2, m-tile mt = blk&3) -> 16 points.
// Builds 16 P rows (split-bf16 packed) in LDS, V16x96 = P @ WB (split-4 MFMA),
// scales by e^pb, stores fp16 V to Vg[panel][96][64] (this block's 16 cols).
// Lanes quad==0 also emit split-bf16 K rows for their point.
__launch_bounds__(64)
__global__ void k_prep(const float* __restrict__ feat, const float* __restrict__ sh,
                       const float* __restrict__ log_s, const float* __restrict__ pos_w,
                       const float* __restrict__ pos_b,
                       const unsigned short* __restrict__ WBH,
                       const unsigned short* __restrict__ WBL,
                       unsigned short* __restrict__ Kgh, unsigned short* __restrict__ Kgl,
                       unsigned short* __restrict__ Vg){
  __shared__ __align__(16) unsigned int Pbuf[16*164];   // 10496 B
  __shared__ unsigned int Po[96*17];                    // 6528 B
  __shared__ float epbs[16];
  int tid = threadIdx.x;
  int lm = tid & 15, quad = tid >> 4;
  int panel = blockIdx.x >> 2, mt = blockIdx.x & 3;
  int idxp = panel*64 + mt*16 + lm;    // this lane's build point
  int n = idxp & (NN-1);
  const float* fp = feat + (size_t)idxp*22;
  const float* shp = sh + n*6;
  float f[22];
  #pragma unroll
  for(int c=0;c<22;c++) f[c]=fp[c];
  float y[6];
  #pragma unroll
  for(int j=0;j<6;j++) y[j]=shp[j];
  // epb
  {
    float pb = pos_b[0];
    #pragma unroll
    for(int j=0;j<6;j++) pb = fmaf(y[j], pos_w[j], pb);
    if(quad==0) epbs[lm] = __expf(pb);
  }
  // K rows (one writer per point)
  if(quad==0){
    float n4=0.f, n6=0.f;
    #pragma unroll
    for(int c=0;c<9;c++) n4 += f[c]*f[c];
    #pragma unroll
    for(int c=9;c<22;c++) n6 += f[c]*f[c];
    n4 = fmaxf(sqrtf(n4), 1e-12f);
    n6 = fmaxf(sqrtf(n6), 1e-12f);
    float s4 = __expf(log_s[0]), s6 = __expf(log_s[1]);
    float a4 = sqrtf(s4)/n4, a6 = sqrtf(s6)/n6;
    unsigned short* kph = Kgh + (size_t)idxp*32;
    unsigned short* kpl = Kgl + (size_t)idxp*32;
    #pragma unroll
    for(int c=0;c<22;c++){
      float qv = f[c] * (c<9 ? a4 : a6);
      unsigned short h = f2bf(qv);
      kph[c]=h; kpl[c]=f2bf(qv - bf2f(h));
    }
    #pragma unroll
    for(int c=22;c<32;c++){ kph[c]=0; kpl[c]=0; }
  }
  // P build: lane covers cols [quad*40, quad*40+40) of point lm
  #pragma unroll
  for(int j4=0;j4<10;j4++){
    u32x4 wv;
    #pragma unroll
    for(int e=0;e<4;e++){
      int c = quad*40 + j4*4 + e;
      float pv;
      if(c<54){ int i=c/6, jj=c-6*i; pv = f[i]*y[jj]; }
      else if(c<132){ int cc=c-54; int i=cc/6, jj=cc-6*i; pv = f[9+i]*y[jj]; }
      else if(c==132) pv = 1.0f;
      else pv = 0.0f;
      wv[e] = pk2r(pv);
    }
    *(u32x4*)&Pbuf[lm*164 + quad*40 + j4*4] = wv;
  }
  __syncthreads();
  // MFMA: V16[16 pts][96] = P @ WB (split-4)
  f32x4 acc[6];
  #pragma unroll
  for(int ft=0;ft<6;ft++)
    #pragma unroll
    for(int i=0;i<4;i++) acc[ft][i]=0.f;
  for(int kc=0;kc<5;kc++){
    const u32x4* ap = (const u32x4*)&Pbuf[lm*164 + kc*32 + quad*8];
    s16x8 Ah, Al;
    unpk(ap[0], ap[1], Ah, Al);
    #pragma unroll
    for(int ft=0;ft<6;ft++){
      size_t bo = (size_t)(ft*16+lm)*160 + kc*32 + quad*8;
      s16x8 Bh = *(const s16x8*)(WBH + bo);
      s16x8 Bl = *(const s16x8*)(WBL + bo);
      f32x4 a = acc[ft];
      a = __builtin_amdgcn_mfma_f32_16x16x32_bf16(Al, Bl, a, 0,0,0);
      a = __builtin_amdgcn_mfma_f32_16x16x32_bf16(Al, Bh, a, 0,0,0);
      a = __builtin_amdgcn_mfma_f32_16x16x32_bf16(Ah, Bl, a, 0,0,0);
      a = __builtin_amdgcn_mfma_f32_16x16x32_bf16(Ah, Bh, a, 0,0,0);
      acc[ft] = a;
    }
  }
  __syncthreads();
  // epilogue: C[pt = quad*4+r][g = ft*16+lm] * epb -> Po[g][pt] as fp16
  #pragma unroll
  for(int r=0;r<4;r++){
    float e = epbs[quad*4 + r];
    #pragma unroll
    for(int ft=0;ft<6;ft++){
      Po[(ft*16+lm)*17 + quad*4 + r] = (unsigned)f2h(acc[ft][r]*e);
    }
  }
  __syncthreads();
  // flush: Vg[panel][g][mt*16 + pt]
  unsigned short* vO = Vg + (size_t)panel*96*64 + mt*16;
  #pragma unroll
  for(int g4=0; g4<24; g4++){
    int g = g4*4 + quad;
    vO[(size_t)g*64 + lm] = (unsigned short)Po[g*17 + lm];
  }
}

// ---------------------------------------------------------------- k_attn
// grid 512 = b(fast) x 2kh x 64qb; block 256 (4 waves), 2 blocks/CU.
// Wave owns one 16-row q-tile, all 96 features, 2048 keys (32 panels).
// S: split-3 bf16, A=K B=Q -> S^T; E,V in single fp16 -> 1 MFMA per PV tile.
// Wave-private XOR-swizzled LDS transpose (conflict-free); zero __syncthreads.
__launch_bounds__(256, 2)
__global__ void k_attn(const unsigned short* __restrict__ Kgh,
                       const unsigned short* __restrict__ Kgl,
                       const unsigned short* __restrict__ Vg,
                       float* __restrict__ ctx0){
  __shared__ __align__(16) unsigned int Ew[4*16*32];   // 8192 B
  int tid = threadIdx.x;
  int lane = tid & 63, w = tid >> 6;
  int lm = lane & 15, quad = lane >> 4;
  int lm7 = lm & 7;
  int blk = blockIdx.x;
  int b = blk & 3, kh = (blk>>2)&1, qb = blk >> 3;   // qb 0..63
  int qt0 = qb*64 + w*16;
  const unsigned short* KhB = Kgh + (size_t)b*NN*32;
  const unsigned short* KlB = Kgl + (size_t)b*NN*32;
  const unsigned short* VB  = Vg  + (size_t)b*64*96*64;
  float* ctx = ctx0 + (size_t)kh*CTXS + (size_t)b*NN*96;
  unsigned int* ew = &Ew[w*512];

  s16x8 qh, ql;
  {
    size_t ro = (size_t)(qt0 + lm)*32 + (size_t)quad*8;
    qh = *(const s16x8*)(KhB + ro);
    ql = *(const s16x8*)(KlB + ro);
  }
  f32x4 acc[6];
  #pragma unroll
  for(int ft=0;ft<6;ft++)
    #pragma unroll
    for(int i=0;i<4;i++) acc[ft][i]=0.f;

  f16x8 Vb[2][12];
  // prologue: V for first panel
  {
    size_t vbase = (size_t)(kh*32)*96*64;
    #pragma unroll
    for(int ft=0;ft<6;ft++)
      #pragma unroll
      for(int ks=0;ks<2;ks++){
        size_t vo = vbase + (size_t)(ft*16+lm)*64 + ks*32 + quad*8;
        Vb[0][ft*2+ks] = *(const f16x8*)(VB + vo);
      }
  }

  #pragma unroll 2
  for(int it=0; it<32; ++it){
    int cur = it&1, nxt = cur^1;
    int panel = kh*32 + it;
    int key0 = panel*64;
    // K loads for this iter (consumed by S below)
    s16x8 k4h[4], k4l[4];
    #pragma unroll
    for(int t=0;t<4;t++){
      size_t ko = (size_t)(key0 + t*16 + lm)*32 + (size_t)quad*8;
      k4h[t] = *(const s16x8*)(KhB + ko);
      k4l[t] = *(const s16x8*)(KlB + ko);
    }
    // V prefetch for next iter (stays in flight across S)
    if(it<31){
      size_t vbase = (size_t)(panel+1)*96*64;
      #pragma unroll
      for(int ft=0;ft<6;ft++)
        #pragma unroll
        for(int ks=0;ks<2;ks++){
          size_t vo = vbase + (size_t)(ft*16+lm)*64 + ks*32 + quad*8;
          Vb[nxt][ft*2+ks] = *(const f16x8*)(VB + vo);
        }
    }
    // S^T (A=K, B=Q): D[m = t*16+quad*4+r][q = lm]; exp -> fp16 -> LDS (swizzled)
    #pragma unroll
    for(int t=0;t<4;t++){
      f32x4 s = {0.f,0.f,0.f,0.f};
      s = __builtin_amdgcn_mfma_f32_16x16x32_bf16(k4l[t], qh, s, 0,0,0);
      s = __builtin_amdgcn_mfma_f32_16x16x32_bf16(k4h[t], ql, s, 0,0,0);
      s = __builtin_amdgcn_mfma_f32_16x16x32_bf16(k4h[t], qh, s, 0,0,0);
      unsigned u01 = (unsigned)f2h(__expf(s[0])) | ((unsigned)f2h(__expf(s[1]))<<16);
      unsigned u23 = (unsigned)f2h(__expf(s[2])) | ((unsigned)f2h(__expf(s[3]))<<16);
      int grp = (t*2 + (quad>>1)) ^ lm7;
      int wi = lm*32 + grp*4 + (quad&1)*2;
      *(u32x2*)&ew[wi] = (u32x2){u01, u23};
    }
    __builtin_amdgcn_wave_barrier();
    // PV: A = E rows (q=lm), B = V; 1 fp16 MFMA per (ks,ft)
    #pragma unroll
    for(int ks=0;ks<2;ks++){
      int grp = (ks*4 + quad) ^ lm7;
      f16x8 e = __builtin_bit_cast(f16x8, *(const u32x4*)&ew[lm*32 + grp*4]);
      #pragma unroll
      for(int ft=0;ft<6;ft++)
        acc[ft] = __builtin_amdgcn_mfma_f32_16x16x32_f16(e, Vb[cur][ft*2+ks], acc[ft], 0,0,0);
    }
    __builtin_amdgcn_wave_barrier();
  }
  // epilogue: D[q][f]: row q = qt0 + quad*4 + r, col f = ft*16 + lm
  #pragma unroll
  for(int ft=0;ft<6;ft++){
    int col = ft*16 + lm;
    #pragma unroll
    for(int r=0;r<4;r++){
      int row = qt0 + quad*4 + r;
      ctx[(size_t)row*96 + col] = acc[ft][r];
    }
  }
}

// ---------------------------------------------------------------- k_out
// block = 8 points x 32 lanes; g = sum of 2 ctx partials (already sc-contracted)
__launch_bounds__(256, 4)
__global__ void k_out(const float* __restrict__ feat, const float* __restrict__ ctxA,
                      const float* __restrict__ w3jout, float* __restrict__ out){
  __shared__ float Wo[10648];
  __shared__ float g[8][96];
  __shared__ float fs[8][24];
  __shared__ float inv[8];
  int tid = threadIdx.x;
  for(int i=tid;i<10648;i+=256) Wo[i]=w3jout[i];
  int p = tid>>5, l5 = tid&31;
  int idx = blockIdx.x*8 + p;
  const float* cp0 = ctxA + (size_t)idx*96;
  const float* cp1 = cp0 + CTXS;
  if(l5<22) fs[p][l5] = feat[(size_t)idx*22 + l5];
  if(l5==22) inv[p] = 1.0f / (cp0[88]+cp1[88]);
  for(int gi=l5; gi<88; gi+=32)
    g[p][gi] = cp0[gi]+cp1[gi];
  __syncthreads();
  if(l5 < 22){
    int grp = (l5 < 9) ? 0 : 1;
    int kk  = grp ? (l5-9) : l5;
    int KD  = grp ? 13 : 9;
    float d = 0.f;
    const int IDs[4]={9,9,13,13}, JDs[4]={9,13,9,13}, FBs[4]={0,0,9,9};
    const int WoOff[8]={0,729,1782,2835,4356,5409,6930,8451};
    const int Goff[8]={0,9,22,31,44,53,66,75};
    #pragma unroll
    for(int s4=0;s4<4;s4++){
      const int ID=IDs[s4], JD=JDs[s4], FB=FBs[s4];
      int wb = (grp ? WoOff[s4+4] : WoOff[s4]) + kk;
      int gb = (grp ? Goff[s4+4] : Goff[s4]);
      for(int i=0;i<ID;i++){
        float fi = fs[p][FB+i];
        for(int j=0;j<JD;j++){
          d = fmaf(fi*g[p][gb+j], Wo[wb + (i*JD+j)*KD], d);
        }
      }
    }
    out[(size_t)idx*22 + l5] = d * inv[p];
  }
}

// ---------------------------------------------------------------- launch
extern "C" void kernel_launch(void* const* d_in, const int* in_sizes, int n_in,
                              void* d_out, int out_size, void* d_ws, size_t ws_size,
                              hipStream_t stream){
  (void)in_sizes; (void)n_in; (void)out_size; (void)ws_size;
  static float h_tab[13336];
  {
    const int vpth[6][3]={{4,0,4},{4,2,4},{6,2,4},{4,2,6},{6,0,6},{6,2,6}};
    const int voff[6]={0,81,486,1071,1656,1825};
    for(int p=0;p<6;p++){
      double scl = std::sqrt((2.0*vpth[p][2]+1.0)/(3.0*CCH));
      compute_w3j(vpth[p][0],vpth[p][1],vpth[p][2],scl,h_tab+voff[p]);
    }
    const int opth[8][3]={{4,4,4},{4,6,4},{6,4,4},{6,6,4},{4,4,6},{4,6,6},{6,4,6},{6,6,6}};
    const int ooff[8]={0,729,1782,2835,4356,5409,6930,8451};
    for(int p=0;p<8;p++){
      double scl = std::sqrt((2.0*opth[p][2]+1.0)/(4.0*CCH*CCH));
      compute_w3j(opth[p][0],opth[p][1],opth[p][2],scl,h_tab+2688+ooff[p]);
    }
  }
  float* wsf=(float*)d_ws;
  hipMemcpyAsync(wsf, h_tab, sizeof(h_tab), hipMemcpyHostToDevice, stream);

  const float* feat =(const float*)d_in[0];
  const float* sh   =(const float*)d_in[1];
  const float* log_s=(const float*)d_in[2];
  const float* pos_w=(const float*)d_in[3];
  const float* pos_b=(const float*)d_in[4];
  const float* wli  =(const float*)d_in[5];
  const float* wval =(const float*)d_in[6];
  const float* wout =(const float*)d_in[7];
  const float* wlo  =(const float*)d_in[8];
  float* outp=(float*)d_out;

  unsigned short* Kgh=(unsigned short*)((char*)d_ws + OFFB_KGH);
  unsigned short* Kgl=(unsigned short*)((char*)d_ws + OFFB_KGL);
  unsigned short* Vg =(unsigned short*)((char*)d_ws + OFFB_VG);
  unsigned short* WBH=(unsigned short*)((char*)d_ws + OFFB_WBH);
  unsigned short* WBL=(unsigned short*)((char*)d_ws + OFFB_WBL);

  hipLaunchKernelGGL(k_weights, dim3(16), dim3(64), 0, stream,
                     wli, wval, wout, wlo, wsf+OFF_W3JVAL, WBH, WBL);
  hipLaunchKernelGGL(k_prep, dim3(1024), dim3(64), 0, stream,
                     feat, sh, log_s, pos_w, pos_b, WBH, WBL,
                     Kgh, Kgl, Vg);
  hipLaunchKernelGGL(k_attn, dim3(512), dim3(256), 0, stream,
                     Kgh, Kgl, Vg, wsf+OFF_CTX0);
  hipLaunchKernelGGL(k_out, dim3(2048), dim3(256), 0, stream,
                     feat, wsf+OFF_CTX0, wsf+OFF_W3JOUT, outp);
}

// Round 10
// 276.144 us; speedup vs baseline: 1.5661x; 1.0295x over previous
//
#include <hip/hip_runtime.h>
#include <cmath>
#include <complex>
#include <vector>

#define NN 4096
#define BB 4
#define CCH 8

// ---- workspace float offsets
#define OFF_W3JVAL 0         // 2670 (pad 2688)
#define OFF_W3JOUT 2688      // 10648 -> 13336 (pad 13440)
#define OFF_CTX0   13568     // 4 partials x 4*4096*96 floats -> ends 6305024 fl
#define CTXS       1572864
// ---- byte offsets, 16B aligned (after ctx: 6305024*4 = 25220096)
#define OFFB_KGH   25220096ULL   // u16[4*4096*32] = 1048576 B
#define OFFB_KGL   26268672ULL
#define OFFB_VG    27317248ULL   // u16[4*64*96*64] fp16 = 3145728 B
#define OFFB_WBH   30462976ULL   // u16[96*160] = 30720 B
#define OFFB_WBL   30493696ULL   // end 30524416

typedef short s16x8 __attribute__((ext_vector_type(8)));
typedef _Float16 f16x8 __attribute__((ext_vector_type(8)));
typedef float f32x4 __attribute__((ext_vector_type(4)));
typedef unsigned int u32x4 __attribute__((ext_vector_type(4)));
typedef unsigned int u32x2 __attribute__((ext_vector_type(2)));

static __device__ __forceinline__ unsigned short f2bf(float x){
  unsigned u = __float_as_uint(x);
  return (unsigned short)((u + 0x7FFFu + ((u >> 16) & 1u)) >> 16);
}
static __device__ __forceinline__ float bf2f(unsigned short h){
  return __uint_as_float(((unsigned)h) << 16);
}
static __device__ __forceinline__ unsigned pk2r(float v){
  unsigned short h = f2bf(v);
  unsigned short l = f2bf(v - bf2f(h));
  return ((unsigned)l << 16) | (unsigned)h;
}
static __device__ __forceinline__ unsigned short f2h(float x){
  return __builtin_bit_cast(unsigned short, (_Float16)x);
}
static __device__ __forceinline__ void unpk(u32x4 a, u32x4 b, s16x8& h, s16x8& l){
  u32x4 hw = { __builtin_amdgcn_perm(a[1],a[0],0x05040100u),
               __builtin_amdgcn_perm(a[3],a[2],0x05040100u),
               __builtin_amdgcn_perm(b[1],b[0],0x05040100u),
               __builtin_amdgcn_perm(b[3],b[2],0x05040100u)};
  u32x4 lw = { __builtin_amdgcn_perm(a[1],a[0],0x07060302u),
               __builtin_amdgcn_perm(a[3],a[2],0x07060302u),
               __builtin_amdgcn_perm(b[1],b[0],0x07060302u),
               __builtin_amdgcn_perm(b[3],b[2],0x07060302u)};
  h = __builtin_bit_cast(s16x8, hw);
  l = __builtin_bit_cast(s16x8, lw);
}
// barrier ordering LDS only: global loads stay in flight (no vmcnt drain).
// The K-loop's only cross-wave traffic is LDS (E tiles), so this is sufficient.
static __device__ __forceinline__ void barrier_lds(){
  __asm__ volatile("s_waitcnt lgkmcnt(0)\n\ts_barrier" ::: "memory");
}

// ---------------------------------------------------------------- host: Wigner 3j
namespace {
double dfact(int n){ double r=1.0; for(int i=2;i<=n;++i) r*=(double)i; return r; }

void compute_w3j(int l1,int l2,int l3,double scale,float* dst){
  int d1=2*l1+1,d2=2*l2+1,d3=2*l3+1;
  std::vector<double> Cc((size_t)d1*d2*d3,0.0);
  for(int i=0;i<d1;i++){int m1=i-l1;
   for(int j=0;j<d2;j++){int m2=j-l2;
    for(int k=0;k<d3;k++){int m3=k-l3;
      if(m1+m2!=m3) continue;
      double pref = std::sqrt((2.0*l3+1.0)*dfact(l3+l1-l2)*dfact(l3-l1+l2)*dfact(l1+l2-l3)/dfact(l1+l2+l3+1));
      pref *= std::sqrt(dfact(l3+m3)*dfact(l3-m3)*dfact(l1-m1)*dfact(l1+m1)*dfact(l2-m2)*dfact(l2+m2));
      double s=0.0;
      for(int kk=0;kk<=l1+l2-l3;kk++){
        int dd[6]={kk,l1+l2-l3-kk,l1-m1-kk,l2+m2-kk,l3-l2+m1+kk,l3-l1-m2+kk};
        int mn=dd[0]; for(int t=1;t<6;t++) if(dd[t]<mn) mn=dd[t];
        if(mn<0) continue;
        double prod=1.0; for(int t=0;t<6;t++) prod*=dfact(dd[t]);
        s += ((kk&1)?-1.0:1.0)/prod;
      }
      Cc[((size_t)i*d2+j)*d3+k]=pref*s;
    }}}
  auto qmat=[](int l){
    int d=2*l+1;
    std::vector<std::complex<double>> q((size_t)d*d,std::complex<double>(0,0));
    double rs2=1.0/std::sqrt(2.0);
    for(int m=-l;m<0;m++){
      q[(size_t)(l+m)*d+(l-m)]=std::complex<double>(rs2,0);
      q[(size_t)(l+m)*d+(l+m)]=std::complex<double>(0,-rs2);
    }
    q[(size_t)l*d+l]=std::complex<double>(1,0);
    for(int m=1;m<=l;m++){
      double sg=(m&1)?-1.0:1.0;
      q[(size_t)(l+m)*d+(l+m)]=std::complex<double>(sg*rs2,0);
      q[(size_t)(l+m)*d+(l-m)]=std::complex<double>(0,sg*rs2);
    }
    std::complex<double> f(1,0),mi(0,-1);
    for(int t=0;t<l;t++) f*=mi;
    for(auto&z:q) z*=f;
    return q;
  };
  auto Q1=qmat(l1),Q2=qmat(l2),Q3=qmat(l3);
  std::vector<std::complex<double>> T1((size_t)d1*d2*d3), T2((size_t)d1*d2*d3);
  for(int j=0;j<d1;j++) for(int k=0;k<d2;k++) for(int m=0;m<d3;m++){
    std::complex<double> s(0,0);
    for(int i=0;i<d1;i++) s += Q1[(size_t)i*d1+j]*Cc[((size_t)i*d2+k)*d3+m];
    T1[((size_t)j*d2+k)*d3+m]=s;
  }
  for(int j=0;j<d1;j++) for(int l=0;l<d2;l++) for(int m=0;m<d3;m++){
    std::complex<double> s(0,0);
    for(int k=0;k<d2;k++) s += Q2[(size_t)k*d2+l]*T1[((size_t)j*d2+k)*d3+m];
    T2[((size_t)j*d2+l)*d3+m]=s;
  }
  std::vector<double> Cr((size_t)d1*d2*d3);
  double nrm=0.0;
  for(int j=0;j<d1;j++) for(int l=0;l<d2;l++) for(int n=0;n<d3;n++){
    std::complex<double> s(0,0);
    for(int m=0;m<d3;m++) s += std::conj(Q3[(size_t)m*d3+n])*T2[((size_t)j*d2+l)*d3+m];
    double v=s.real();
    Cr[((size_t)j*d2+l)*d3+n]=v; nrm+=v*v;
  }
  nrm=std::sqrt(nrm);
  double c=scale/nrm;
  for(size_t t=0;t<Cr.size();t++) dst[t]=(float)(Cr[t]*c);
}
} // namespace

// ---------------------------------------------------------------- k_weights
// grid 16 x 64. Builds WB[96][160] split-bf16; folds w3j with A[p][i3].
__global__ void k_weights(const float* __restrict__ wli, const float* __restrict__ wval,
                          const float* __restrict__ wout, const float* __restrict__ wlo,
                          const float* __restrict__ Wv,
                          unsigned short* __restrict__ WBH, unsigned short* __restrict__ WBL){
  __shared__ float bws[48];
  __shared__ float scs[64];
  __shared__ float As[24];
  int t = threadIdx.x;
  if(t<48){
    const int val_l1[6]={0,0,1,0,1,1};
    int p=t>>3, w=t&7;
    float s=0.f;
    for(int u=0;u<8;u++) s = fmaf(wli[val_l1[p]*8+u], wval[(p*8+u)*8+w], s);
    bws[t]=s;
  }
  {
    const int out_l1[8]={0,0,1,1,0,0,1,1};
    const int out_l3[8]={0,0,0,0,1,1,1,1};
    int p=t>>3, v=t&7;
    float s=0.f;
    for(int u=0;u<8;u++){
      float a=wli[out_l1[p]*8+u];
      for(int w=0;w<8;w++) s = fmaf(wout[((p*8+u)*8+v)*8+w]*a, wlo[out_l3[p]*8+w], s);
    }
    scs[t]=s*0.35355339059327373f; // 1/sqrt(8)
  }
  __syncthreads();
  if(t<24){
    int p=t/3, i3=t-3*p;
    int vp = (p&1)*3 + i3;
    float s=0.f;
    for(int w=0;w<8;w++) s = fmaf(scs[p*8+w], bws[vp*8+w], s);
    As[t]=s;
  }
  __syncthreads();
  int base = blockIdx.x*960;
  for(int k=0;k<15;k++){
    int cell = base + k*64 + t;
    int f = cell/160, c = cell - f*160;
    float v = 0.f;
    if(f < 88 && c < 132){
      int seg = f/22, off = f - seg*22;
      int even = (off < 9);
      int p = 2*seg + (even?0:1);
      int jo = even ? off : off-9;
      int l1, i, jj;
      if(c < 54){ l1=4; i=c/6; jj=c-6*i; }
      else { int cc=c-54; l1=6; i=cc/6; jj=cc-6*i; }
      if(even){
        if(l1==4 && jj==0)      v = As[p*3+0]*Wv[i*9+jo];
        else if(l1==4)          v = As[p*3+1]*Wv[81+(i*5+jj-1)*9+jo];
        else if(jj>=1)          v = As[p*3+2]*Wv[486+(i*5+jj-1)*9+jo];
      } else {
        if(l1==4 && jj>=1)      v = As[p*3+0]*Wv[1071+(i*5+jj-1)*13+jo];
        else if(l1==6 && jj==0) v = As[p*3+1]*Wv[1656+i*13+jo];
        else if(l1==6)          v = As[p*3+2]*Wv[1825+(i*5+jj-1)*13+jo];
      }
    } else if(f==88 && c==132){
      v = 1.0f;
    }
    unsigned short h = f2bf(v);
    WBH[cell] = h;
    WBL[cell] = f2bf(v - bf2f(h));
  }
}

// ---------------------------------------------------------------- k_prep (MFMA)
// grid 1024 x 64: block = (panel = blk>>2, m-tile mt = blk&3) -> 16 points.
// 16 P rows (split-bf16) in LDS; V16x96 = P @ WB (split-4 MFMA); scale e^pb;
// fp16 V to Vg[panel][96][64] (paired u32 stores). quad==0 lanes emit K rows.
__launch_bounds__(64)
__global__ void k_prep(const float* __restrict__ feat, const float* __restrict__ sh,
                       const float* __restrict__ log_s, const float* __restrict__ pos_w,
                       const float* __restrict__ pos_b,
                       const unsigned short* __restrict__ WBH,
                       const unsigned short* __restrict__ WBL,
                       unsigned short* __restrict__ Kgh, unsigned short* __restrict__ Kgl,
                       unsigned short* __restrict__ Vg){
  __shared__ __align__(16) unsigned int Pbuf[16*164];   // 10496 B
  __shared__ unsigned int Po[96*17];                    // 6528 B
  __shared__ float epbs[16];
  int tid = threadIdx.x;
  int lm = tid & 15, quad = tid >> 4;
  int panel = blockIdx.x >> 2, mt = blockIdx.x & 3;
  int idxp = panel*64 + mt*16 + lm;
  int n = idxp & (NN-1);
  const float* fp = feat + (size_t)idxp*22;
  const float* shp = sh + n*6;
  float f[22];
  #pragma unroll
  for(int c=0;c<22;c++) f[c]=fp[c];
  float y[6];
  #pragma unroll
  for(int j=0;j<6;j++) y[j]=shp[j];
  {
    float pb = pos_b[0];
    #pragma unroll
    for(int j=0;j<6;j++) pb = fmaf(y[j], pos_w[j], pb);
    if(quad==0) epbs[lm] = __expf(pb);
  }
  if(quad==0){
    float n4=0.f, n6=0.f;
    #pragma unroll
    for(int c=0;c<9;c++) n4 += f[c]*f[c];
    #pragma unroll
    for(int c=9;c<22;c++) n6 += f[c]*f[c];
    n4 = fmaxf(sqrtf(n4), 1e-12f);
    n6 = fmaxf(sqrtf(n6), 1e-12f);
    float s4 = __expf(log_s[0]), s6 = __expf(log_s[1]);
    float a4 = sqrtf(s4)/n4, a6 = sqrtf(s6)/n6;
    unsigned short* kph = Kgh + (size_t)idxp*32;
    unsigned short* kpl = Kgl + (size_t)idxp*32;
    #pragma unroll
    for(int c=0;c<22;c++){
      float qv = f[c] * (c<9 ? a4 : a6);
      unsigned short h = f2bf(qv);
      kph[c]=h; kpl[c]=f2bf(qv - bf2f(h));
    }
    #pragma unroll
    for(int c=22;c<32;c++){ kph[c]=0; kpl[c]=0; }
  }
  // P build: lane covers cols [quad*40, quad*40+40) of point lm
  #pragma unroll
  for(int j4=0;j4<10;j4++){
    u32x4 wv;
    #pragma unroll
    for(int e=0;e<4;e++){
      int c = quad*40 + j4*4 + e;
      float pv;
      if(c<54){ int i=c/6, jj=c-6*i; pv = f[i]*y[jj]; }
      else if(c<132){ int cc=c-54; int i=cc/6, jj=cc-6*i; pv = f[9+i]*y[jj]; }
      else if(c==132) pv = 1.0f;
      else pv = 0.0f;
      wv[e] = pk2r(pv);
    }
    *(u32x4*)&Pbuf[lm*164 + quad*40 + j4*4] = wv;
  }
  __syncthreads();
  f32x4 acc[6];
  #pragma unroll
  for(int ft=0;ft<6;ft++)
    #pragma unroll
    for(int i=0;i<4;i++) acc[ft][i]=0.f;
  for(int kc=0;kc<5;kc++){
    const u32x4* ap = (const u32x4*)&Pbuf[lm*164 + kc*32 + quad*8];
    s16x8 Ah, Al;
    unpk(ap[0], ap[1], Ah, Al);
    #pragma unroll
    for(int ft=0;ft<6;ft++){
      size_t bo = (size_t)(ft*16+lm)*160 + kc*32 + quad*8;
      s16x8 Bh = *(const s16x8*)(WBH + bo);
      s16x8 Bl = *(const s16x8*)(WBL + bo);
      f32x4 a = acc[ft];
      a = __builtin_amdgcn_mfma_f32_16x16x32_bf16(Al, Bl, a, 0,0,0);
      a = __builtin_amdgcn_mfma_f32_16x16x32_bf16(Al, Bh, a, 0,0,0);
      a = __builtin_amdgcn_mfma_f32_16x16x32_bf16(Ah, Bl, a, 0,0,0);
      a = __builtin_amdgcn_mfma_f32_16x16x32_bf16(Ah, Bh, a, 0,0,0);
      acc[ft] = a;
    }
  }
  __syncthreads();
  // epilogue: C[pt=quad*4+r][g=ft*16+lm] * epb -> Po[g][pt] fp16
  #pragma unroll
  for(int r=0;r<4;r++){
    float e = epbs[quad*4 + r];
    #pragma unroll
    for(int ft=0;ft<6;ft++){
      Po[(ft*16+lm)*17 + quad*4 + r] = (unsigned)f2h(acc[ft][r]*e);
    }
  }
  __syncthreads();
  // flush: paired u32 stores, Vg32[g][mt*8 + j], points 2j,2j+1
  unsigned int* vO32 = (unsigned int*)(Vg + (size_t)panel*96*64);
  #pragma unroll
  for(int wv=0; wv<12; wv++){
    int idx2 = wv*64 + tid;         // 0..767
    int g = idx2 >> 3, j = idx2 & 7;
    unsigned lo = Po[g*17 + 2*j] & 0xFFFFu;
    unsigned hi = Po[g*17 + 2*j + 1] & 0xFFFFu;
    vO32[g*32 + mt*8 + j] = lo | (hi<<16);
  }
}

// ---------------------------------------------------------------- k_attn
// grid 512 = 4b(fast) x 4kh x 32qb; block 512 (8 waves), BM=128, 16 panels.
// Wave (sq=w&3, sk=w>>2): S covers q-tiles {2sq,2sq+1} x k-tiles {2sk,2sk+1}
// (split-3 bf16, A=K B=Q -> S^T); PV covers q-tiles {2sq,2sq+1} x f-tiles
// {3sk..3sk+2} (fp16 E,V -> 1 MFMA/tile). E through LDS, lgkm-only barriers:
// K/V global loads issued at iter top stay in flight across barriers.
#define EST 72   // u16 stride: 144 B rows (16B-aligned), <=2-way banks (free)
__launch_bounds__(512, 4)
__global__ void k_attn(const unsigned short* __restrict__ Kgh,
                       const unsigned short* __restrict__ Kgl,
                       const unsigned short* __restrict__ Vg,
                       float* __restrict__ ctx0){
  __shared__ __align__(16) unsigned short Es[128*EST];   // 18432 B
  int tid = threadIdx.x;
  int lane = tid & 63, w = tid >> 6;
  int lm = lane & 15, quad = lane >> 4;
  int blk = blockIdx.x;
  int b = blk & 3, kh = (blk>>2)&3, qb = blk >> 4;   // qb 0..31
  int qrow0 = qb * 128;
  const unsigned short* KhB = Kgh + (size_t)b*NN*32;
  const unsigned short* KlB = Kgl + (size_t)b*NN*32;
  const unsigned short* VB  = Vg  + (size_t)b*64*96*64;
  float* ctx = ctx0 + (size_t)kh*CTXS + (size_t)b*NN*96;

  int sq = w & 3;    // q-tile pair {2sq, 2sq+1}
  int sk = w >> 2;   // S k-tile pair {2sk,2sk+1}; PV f-group {3sk..3sk+2}

  s16x8 qh[2], ql[2];
  #pragma unroll
  for(int q2=0;q2<2;q2++){
    size_t ro = (size_t)(qrow0 + (2*sq+q2)*16 + lm)*32 + (size_t)quad*8;
    qh[q2] = *(const s16x8*)(KhB + ro);
    ql[q2] = *(const s16x8*)(KlB + ro);
  }
  f32x4 acc[2][3];
  #pragma unroll
  for(int q2=0;q2<2;q2++)
    #pragma unroll
    for(int ft=0;ft<3;ft++)
      #pragma unroll
      for(int i=0;i<4;i++) acc[q2][ft][i]=0.f;

  #pragma unroll 1
  for(int it=0; it<16; ++it){
    int panel = kh*16 + it;
    int key0 = panel*64;
    // K loads (consumed by S below)
    s16x8 kfh[2], kfl[2];
    #pragma unroll
    for(int k2=0;k2<2;k2++){
      size_t ko = (size_t)(key0 + (2*sk+k2)*16 + lm)*32 + (size_t)quad*8;
      kfh[k2] = *(const s16x8*)(KhB + ko);
      kfl[k2] = *(const s16x8*)(KlB + ko);
    }
    // V loads (fp16) — in flight across the barriers, used in PV
    f16x8 vv[2][3];
    #pragma unroll
    for(int ks=0;ks<2;ks++)
      #pragma unroll
      for(int ft=0;ft<3;ft++){
        size_t vo = (size_t)panel*96*64 + (size_t)((3*sk+ft)*16+lm)*64 + ks*32 + quad*8;
        vv[ks][ft] = *(const f16x8*)(VB + vo);
      }
    // S^T (A=K, B=Q): D[key = (2sk+k2)*16+quad*4+r][q = (2sq+q2) tile, col lm]
    unsigned p01[2][2], p23[2][2];
    #pragma unroll
    for(int k2=0;k2<2;k2++)
      #pragma unroll
      for(int q2=0;q2<2;q2++){
        f32x4 s = {0.f,0.f,0.f,0.f};
        s = __builtin_amdgcn_mfma_f32_16x16x32_bf16(kfl[k2], qh[q2], s, 0,0,0);
        s = __builtin_amdgcn_mfma_f32_16x16x32_bf16(kfh[k2], ql[q2], s, 0,0,0);
        s = __builtin_amdgcn_mfma_f32_16x16x32_bf16(kfh[k2], qh[q2], s, 0,0,0);
        p01[k2][q2] = (unsigned)f2h(__expf(s[0])) | ((unsigned)f2h(__expf(s[1]))<<16);
        p23[k2][q2] = (unsigned)f2h(__expf(s[2])) | ((unsigned)f2h(__expf(s[3]))<<16);
      }
    barrier_lds();   // prior-iter PV reads of Es done (lgkm only)
    #pragma unroll
    for(int k2=0;k2<2;k2++)
      #pragma unroll
      for(int q2=0;q2<2;q2++){
        int row = (2*sq+q2)*16 + lm;
        int key = (2*sk+k2)*16 + quad*4;
        *(u32x2*)&Es[row*EST + key] = (u32x2){p01[k2][q2], p23[k2][q2]};
      }
    barrier_lds();   // Es visible
    // PV: A = E rows (m=q=lm), B = V (n=f=lm); 1 fp16 MFMA per (ks,ft,q2)
    #pragma unroll
    for(int ks=0;ks<2;ks++){
      #pragma unroll
      for(int q2=0;q2<2;q2++){
        f16x8 e = *(const f16x8*)&Es[((2*sq+q2)*16 + lm)*EST + ks*32 + quad*8];
        #pragma unroll
        for(int ft=0;ft<3;ft++)
          acc[q2][ft] = __builtin_amdgcn_mfma_f32_16x16x32_f16(e, vv[ks][ft], acc[q2][ft], 0,0,0);
      }
    }
  }
  // epilogue: D[q][f]: row = qrow0+(2sq+q2)*16+quad*4+r, col = (3sk+ft)*16+lm
  #pragma unroll
  for(int q2=0;q2<2;q2++){
    #pragma unroll
    for(int ft=0;ft<3;ft++){
      int col = (3*sk+ft)*16 + lm;
      #pragma unroll
      for(int r=0;r<4;r++){
        int row = qrow0 + (2*sq+q2)*16 + quad*4 + r;
        ctx[(size_t)row*96 + col] = acc[q2][ft][r];
      }
    }
  }
}

// ---------------------------------------------------------------- k_out
// grid 512 x 256: 32 points/block (4 groups of 8), table loaded once.
// g = sum of 4 ctx partials (already sc-contracted).
__launch_bounds__(256, 4)
__global__ void k_out(const float* __restrict__ feat, const float* __restrict__ ctxA,
                      const float* __restrict__ w3jout, float* __restrict__ out){
  __shared__ float Wo[10648];
  __shared__ float g[8][96];
  __shared__ float fs[8][24];
  __shared__ float inv[8];
  int tid = threadIdx.x;
  for(int i=tid;i<10648;i+=256) Wo[i]=w3jout[i];
  int p = tid>>5, l5 = tid&31;
  for(int pp=0; pp<4; ++pp){
    if(pp) __syncthreads();
    int idx = blockIdx.x*32 + pp*8 + p;
    const float* cp0 = ctxA + (size_t)idx*96;
    const float* cp1 = cp0 + CTXS;
    const float* cp2 = cp0 + 2*CTXS;
    const float* cp3 = cp0 + 3*CTXS;
    if(l5<22) fs[p][l5] = feat[(size_t)idx*22 + l5];
    if(l5==22) inv[p] = 1.0f / (cp0[88]+cp1[88]+cp2[88]+cp3[88]);
    for(int gi=l5; gi<88; gi+=32)
      g[p][gi] = cp0[gi]+cp1[gi]+cp2[gi]+cp3[gi];
    __syncthreads();
    if(l5 < 22){
      int grp = (l5 < 9) ? 0 : 1;
      int kk  = grp ? (l5-9) : l5;
      int KD  = grp ? 13 : 9;
      float d = 0.f;
      const int IDs[4]={9,9,13,13}, JDs[4]={9,13,9,13}, FBs[4]={0,0,9,9};
      const int WoOff[8]={0,729,1782,2835,4356,5409,6930,8451};
      const int Goff[8]={0,9,22,31,44,53,66,75};
      #pragma unroll
      for(int s4=0;s4<4;s4++){
        const int ID=IDs[s4], JD=JDs[s4], FB=FBs[s4];
        int wb = (grp ? WoOff[s4+4] : WoOff[s4]) + kk;
        int gb = (grp ? Goff[s4+4] : Goff[s4]);
        for(int i=0;i<ID;i++){
          float fi = fs[p][FB+i];
          for(int j=0;j<JD;j++){
            d = fmaf(fi*g[p][gb+j], Wo[wb + (i*JD+j)*KD], d);
          }
        }
      }
      out[(size_t)idx*22 + l5] = d * inv[p];
    }
  }
}

// ---------------------------------------------------------------- launch
extern "C" void kernel_launch(void* const* d_in, const int* in_sizes, int n_in,
                              void* d_out, int out_size, void* d_ws, size_t ws_size,
                              hipStream_t stream){
  (void)in_sizes; (void)n_in; (void)out_size; (void)ws_size;
  static float h_tab[13336];
  {
    const int vpth[6][3]={{4,0,4},{4,2,4},{6,2,4},{4,2,6},{6,0,6},{6,2,6}};
    const int voff[6]={0,81,486,1071,1656,1825};
    for(int p=0;p<6;p++){
      double scl = std::sqrt((2.0*vpth[p][2]+1.0)/(3.0*CCH));
      compute_w3j(vpth[p][0],vpth[p][1],vpth[p][2],scl,h_tab+voff[p]);
    }
    const int opth[8][3]={{4,4,4},{4,6,4},{6,4,4},{6,6,4},{4,4,6},{4,6,6},{6,4,6},{6,6,6}};
    const int ooff[8]={0,729,1782,2835,4356,5409,6930,8451};
    for(int p=0;p<8;p++){
      double scl = std::sqrt((2.0*opth[p][2]+1.0)/(4.0*CCH*CCH));
      compute_w3j(opth[p][0],opth[p][1],opth[p][2],scl,h_tab+2688+ooff[p]);
    }
  }
  float* wsf=(float*)d_ws;
  hipMemcpyAsync(wsf, h_tab, sizeof(h_tab), hipMemcpyHostToDevice, stream);

  const float* feat =(const float*)d_in[0];
  const float* sh   =(const float*)d_in[1];
  const float* log_s=(const float*)d_in[2];
  const float* pos_w=(const float*)d_in[3];
  const float* pos_b=(const float*)d_in[4];
  const float* wli  =(const float*)d_in[5];
  const float* wval =(const float*)d_in[6];
  const float* wout =(const float*)d_in[7];
  const float* wlo  =(const float*)d_in[8];
  float* outp=(float*)d_out;

  unsigned short* Kgh=(unsigned short*)((char*)d_ws + OFFB_KGH);
  unsigned short* Kgl=(unsigned short*)((char*)d_ws + OFFB_KGL);
  unsigned short* Vg =(unsigned short*)((char*)d_ws + OFFB_VG);
  unsigned short* WBH=(unsigned short*)((char*)d_ws + OFFB_WBH);
  unsigned short* WBL=(unsigned short*)((char*)d_ws + OFFB_WBL);

  hipLaunchKernelGGL(k_weights, dim3(16), dim3(64), 0, stream,
                     wli, wval, wout, wlo, wsf+OFF_W3JVAL, WBH, WBL);
  hipLaunchKernelGGL(k_prep, dim3(1024), dim3(64), 0, stream,
                     feat, sh, log_s, pos_w, pos_b, WBH, WBL,
                     Kgh, Kgl, Vg);
  hipLaunchKernelGGL(k_attn, dim3(512), dim3(512), 0, stream,
                     Kgh, Kgl, Vg, wsf+OFF_CTX0);
  hipLaunchKernelGGL(k_out, dim3(512), dim3(256), 0, stream,
                     feat, wsf+OFF_CTX0, wsf+OFF_W3JOUT, outp);
}